// Round 15
// baseline (691.230 us; speedup 1.0000x reference)
//
#include <hip/hip_runtime.h>
#include <math.h>

#define NN 50000   // nodes
#define NE 800000  // edges
#define HH 64      // hidden
#define NB 2048    // batch |y|
#define NPAD 53248 // padded cols = 832 tiles of 64
#define NST2 32    // column stripes in fused final kernel
#define TPS2 26    // tiles per stripe (32*26 = 832)
#define LOG2E 1.4426950408889634f
#define HBLK 3125  // hist blocks in fused k_hq
#define QBLK 782   // qkvs blocks in fused k_hq

typedef __attribute__((ext_vector_type(8))) short bf16x8;
typedef __attribute__((ext_vector_type(4))) float f32x4;

__device__ inline ushort f2bf(float f) {  // round-to-nearest-even f32->bf16
  uint u = __float_as_uint(f);
  uint r = (u + 0x7fffu + ((u >> 16) & 1u)) >> 16;
  return (ushort)r;
}
__device__ inline float bf2f(uint u) { return __uint_as_float(u << 16); }

__device__ inline float fexp2(float x) {
#if __has_builtin(__builtin_amdgcn_exp2f)
  return __builtin_amdgcn_exp2f(x);
#else
  return exp2f(x);
#endif
}

// ---------------- prep: zero counters/flags/bar + fragment-permuted W1 + eb + WT ----------------
__global__ __launch_bounds__(256) void k_prep(
    const float* __restrict__ W1, const float* __restrict__ b1,
    const float* __restrict__ Wq, const float* __restrict__ Wk,
    const float* __restrict__ Wv, const float* __restrict__ Ws,
    ushort* __restrict__ w1p, float* __restrict__ eb, ushort* __restrict__ WT,
    int* cnt_d, int* cnt_s, char* flag, char* ymark, int* bar)
{
  int i = blockIdx.x * 256 + threadIdx.x;  // grid 224*256 = 57344 >= NPAD
  if (i < NN) { cnt_d[i] = 0; cnt_s[i] = 0; flag[i] = 0; ymark[i] = 0; }
  if (i == 0) *bar = 0;
  if (i < 4 * HH * HH) {
    int m = i >> 12, rem = i & 4095;
    int c = rem >> 6, kk = rem & 63;
    const float* W = (m == 0) ? Wq : (m == 1) ? Wk : (m == 2) ? Wv : Ws;
    WT[i] = f2bf(W[kk * HH + c]);
  }
  if (i < NPAD) {
    eb[i] = (i < NN) ? __expf(b1[i]) : 0.f;
    uint4 o[8];
    ushort* op = (ushort*)o;
    if (i < NN) {
#pragma unroll
      for (int k = 0; k < HH; ++k) op[k] = f2bf(W1[(size_t)k * NN + i] * LOG2E);
    } else {
#pragma unroll
      for (int k = 0; k < HH; ++k) op[k] = 0;
    }
    int t = i >> 6, nt = (i >> 4) & 3, lr = i & 15;
    ushort* tp = w1p + (size_t)t * 4096;
#pragma unroll
    for (int kt = 0; kt < 2; ++kt)
#pragma unroll
      for (int lk = 0; lk < 4; ++lk)
        *(uint4*)(tp + (kt * 4 + nt) * 512 + (lk * 16 + lr) * 8) = o[kt * 4 + lk];
  }
}

// ---------------- mark y-membership ----------------
__global__ __launch_bounds__(256) void k_mark(const int* __restrict__ y,
                                              char* __restrict__ ymark) {
  int i = blockIdx.x * 256 + threadIdx.x;
  if (i < NB) ymark[y[i]] = 1;
}

// ---------------- FUSED: hist (blocks 0..HBLK-1) + qkvs (blocks HBLK..) ----------------
__global__ __launch_bounds__(256) void k_hq(
    const int* __restrict__ src, const int* __restrict__ dst,
    const char* __restrict__ ymark,
    int* cnt_s, int* cnt_d, char* __restrict__ flag,
    int* __restrict__ rank_d, int* __restrict__ rank_s,
    const int* __restrict__ x, const float* __restrict__ emb,
    const ushort* __restrict__ WT,
    const float* __restrict__ bq, const float* __restrict__ bk,
    const float* __restrict__ bv, const float* __restrict__ bs,
    ushort* __restrict__ qb, ushort* __restrict__ kb, ushort* __restrict__ vb,
    float* __restrict__ hs)
{
  if (blockIdx.x < HBLK) {
    int e = blockIdx.x * 256 + threadIdx.x;
    if (e < NE) {
      int s = src[e], d = dst[e];
      rank_d[e] = atomicAdd(&cnt_d[d], 1);
      if (ymark[s]) {
        rank_s[e] = atomicAdd(&cnt_s[s], 1);
        flag[d] = 1;
      } else {
        rank_s[e] = -1;
      }
    }
    return;
  }
  // ---- qkvs part ----
  int l = threadIdx.x & 63, w = threadIdx.x >> 6;
  int lr = l & 15, lk = l >> 4;
  int r0 = (blockIdx.x - HBLK) * 64;
  const ushort* wt = WT + w * HH * HH;
  const float* B = (w == 0) ? bq : (w == 1) ? bk : (w == 2) ? bv : bs;

  bf16x8 b[2][4];
#pragma unroll
  for (int kt = 0; kt < 2; ++kt)
#pragma unroll
    for (int nt = 0; nt < 4; ++nt)
      b[kt][nt] = *(const bf16x8*)(wt + (nt * 16 + lr) * HH + kt * 32 + lk * 8);

  bf16x8 a[2][4];
#pragma unroll
  for (int mt = 0; mt < 4; ++mt) {
    int row = r0 + mt * 16 + lr;
    int g = (row < NN) ? x[row] : 0;
    const float* hp = emb + (size_t)g * HH;
#pragma unroll
    for (int kt = 0; kt < 2; ++kt) {
      float4 f0 = *(const float4*)(hp + kt * 32 + lk * 8);
      float4 f1 = *(const float4*)(hp + kt * 32 + lk * 8 + 4);
      bf16x8 af;
      af[0] = f2bf(f0.x); af[1] = f2bf(f0.y); af[2] = f2bf(f0.z); af[3] = f2bf(f0.w);
      af[4] = f2bf(f1.x); af[5] = f2bf(f1.y); af[6] = f2bf(f1.z); af[7] = f2bf(f1.w);
      a[kt][mt] = af;
    }
  }

  f32x4 acc[4][4];
  const f32x4 z4 = {0.f, 0.f, 0.f, 0.f};
#pragma unroll
  for (int mt = 0; mt < 4; ++mt)
#pragma unroll
    for (int nt = 0; nt < 4; ++nt) acc[mt][nt] = z4;
#pragma unroll
  for (int kt = 0; kt < 2; ++kt)
#pragma unroll
    for (int mt = 0; mt < 4; ++mt)
#pragma unroll
      for (int nt = 0; nt < 4; ++nt)
        acc[mt][nt] = __builtin_amdgcn_mfma_f32_16x16x32_bf16(a[kt][mt], b[kt][nt], acc[mt][nt], 0, 0, 0);

  if (w < 3) {
    ushort* Db = (w == 0) ? qb : (w == 1) ? kb : vb;
#pragma unroll
    for (int mt = 0; mt < 4; ++mt)
#pragma unroll
      for (int r = 0; r < 4; ++r) {
        int row = r0 + mt * 16 + lk * 4 + r;
        if (row < NN) {
#pragma unroll
          for (int nt = 0; nt < 4; ++nt) {
            int c = nt * 16 + lr;
            Db[(size_t)row * HH + c] = f2bf(acc[mt][nt][r] + B[c]);
          }
        }
      }
  } else {
#pragma unroll
    for (int mt = 0; mt < 4; ++mt)
#pragma unroll
      for (int r = 0; r < 4; ++r) {
        int row = r0 + mt * 16 + lk * 4 + r;
        if (row < NN) {
#pragma unroll
          for (int nt = 0; nt < 4; ++nt) {
            int c = nt * 16 + lr;
            hs[(size_t)row * HH + c] = acc[mt][nt][r] + B[c];
          }
        }
      }
  }
}

// ---------------- CSR build: exclusive scan (1 block per array) ----------------
__global__ __launch_bounds__(1024) void k_scan(
    const int* __restrict__ cnt_d, int* indptr_d,
    const int* __restrict__ cnt_s, int* indptr_s)
{
  const int* cnt = (blockIdx.x == 0) ? cnt_d : cnt_s;
  int* indptr    = (blockIdx.x == 0) ? indptr_d : indptr_s;
  __shared__ int sums[1024];
  const int CH = (NN + 1023) / 1024;  // 49
  int t = threadIdx.x;
  int begin = t * CH;
  int end = begin + CH; if (end > NN) end = NN;
  int s = 0;
  for (int i = begin; i < end; ++i) s += cnt[i];
  sums[t] = s;
  __syncthreads();
  for (int off = 1; off < 1024; off <<= 1) {
    int val = (t >= off) ? sums[t - off] : 0;
    __syncthreads();
    sums[t] += val;
    __syncthreads();
  }
  int prefix = (t == 0) ? 0 : sums[t - 1];
  for (int i = begin; i < end; ++i) {
    indptr[i] = prefix;
    prefix += cnt[i];
  }
  if (t == 0) indptr[NN] = sums[1023];
}

// ---------------- fused logits (flag-gated, bf16) + rank-addressed CSR fill ----------------
__global__ __launch_bounds__(256) void k_efill(
    const int* __restrict__ src, const int* __restrict__ dst,
    const ushort* __restrict__ qb, const ushort* __restrict__ kb,
    const char* __restrict__ flag,
    const int* __restrict__ indptr_s, const int* __restrict__ indptr_d,
    const int* __restrict__ rank_d, const int* __restrict__ rank_s,
    int* __restrict__ dstlist_s, int2* __restrict__ slot_d)
{
  int gid = blockIdx.x * 256 + threadIdx.x;
  int e = gid >> 2;
  int lane = gid & 3;
  if (e >= NE) return;
  int s = src[e], d = dst[e];
  bool fd = flag[d];
  float p = 0.f;
  if (fd) {
    const uint4* qp = (const uint4*)(qb + (size_t)d * HH + lane * 16);
    const uint4* kp = (const uint4*)(kb + (size_t)s * HH + lane * 16);
    uint4 qa0 = qp[0], ka0 = kp[0];
    uint4 qa1 = qp[1], ka1 = kp[1];
    p += bf2f(qa0.x & 0xffffu) * bf2f(ka0.x & 0xffffu) + bf2f(qa0.x >> 16) * bf2f(ka0.x >> 16);
    p += bf2f(qa0.y & 0xffffu) * bf2f(ka0.y & 0xffffu) + bf2f(qa0.y >> 16) * bf2f(ka0.y >> 16);
    p += bf2f(qa0.z & 0xffffu) * bf2f(ka0.z & 0xffffu) + bf2f(qa0.z >> 16) * bf2f(ka0.z >> 16);
    p += bf2f(qa0.w & 0xffffu) * bf2f(ka0.w & 0xffffu) + bf2f(qa0.w >> 16) * bf2f(ka0.w >> 16);
    p += bf2f(qa1.x & 0xffffu) * bf2f(ka1.x & 0xffffu) + bf2f(qa1.x >> 16) * bf2f(ka1.x >> 16);
    p += bf2f(qa1.y & 0xffffu) * bf2f(ka1.y & 0xffffu) + bf2f(qa1.y >> 16) * bf2f(ka1.y >> 16);
    p += bf2f(qa1.z & 0xffffu) * bf2f(ka1.z & 0xffffu) + bf2f(qa1.z >> 16) * bf2f(ka1.z >> 16);
    p += bf2f(qa1.w & 0xffffu) * bf2f(ka1.w & 0xffffu) + bf2f(qa1.w >> 16) * bf2f(ka1.w >> 16);
    p += __shfl_xor(p, 2);
    p += __shfl_xor(p, 1);
  }
  if (lane == 0) {
    if (fd) {
      int pd = indptr_d[d] + rank_d[e];
      int2 sl; sl.x = s; sl.y = __float_as_int(p * (0.125f * LOG2E));
      slot_d[pd] = sl;
    }
    int rs = rank_s[e];
    if (rs >= 0) dstlist_s[indptr_s[s] + rs] = d;
  }
}

// ---------------- per-dst softmax + weighted v aggregation (flagged only) ----------------
__global__ __launch_bounds__(256) void k_agg(
    const int* __restrict__ indptr_d, const int2* __restrict__ slot_d,
    const ushort* __restrict__ vb, const char* __restrict__ flag,
    float* __restrict__ hs)
{
  int w = (blockIdx.x * 256 + threadIdx.x) >> 6;  // node id, one wave each
  int lane = threadIdx.x & 63;                    // hidden dim
  if (w >= NN) return;
  if (!flag[w]) return;
  int beg = indptr_d[w], end = indptr_d[w + 1];
  if (beg == end) return;
  float den0 = 0.f, den1 = 0.f, acc0 = 0.f, acc1 = 0.f;
  int j = beg;
  for (; j + 1 < end; j += 2) {
    int2 sa = slot_d[j];
    int2 sb = slot_d[j + 1];
    float pa = fexp2(__int_as_float(sa.y));
    float pb = fexp2(__int_as_float(sb.y));
    float va = bf2f((uint)vb[(size_t)sa.x * HH + lane]);
    float vc = bf2f((uint)vb[(size_t)sb.x * HH + lane]);
    den0 += pa; den1 += pb;
    acc0 = fmaf(pa, va, acc0);
    acc1 = fmaf(pb, vc, acc1);
  }
  if (j < end) {
    int2 sa = slot_d[j];
    float pa = fexp2(__int_as_float(sa.y));
    den0 += pa;
    acc0 = fmaf(pa, bf2f((uint)vb[(size_t)sa.x * HH + lane]), acc0);
  }
  hs[(size_t)w * HH + lane] += (acc0 + acc1) / (den0 + den1);
}

// ---------------- new_x[b] = sum_{e: src==y[b]} out[dst[e]]  (written as bf16) ----------------
__global__ __launch_bounds__(256) void k_newx(
    const int* __restrict__ y, const int* __restrict__ indptr_s,
    const int* __restrict__ dstlist_s, const float* __restrict__ outn,
    ushort* __restrict__ nxbf)
{
  int w = (blockIdx.x * 256 + threadIdx.x) >> 6;
  int lane = threadIdx.x & 63;
  if (w >= NB) return;
  int u = y[w];
  int beg = indptr_s[u], end = indptr_s[u + 1];
  float acc = 0.f;
  for (int j = beg; j < end; ++j) acc += outn[(size_t)dstlist_s[j] * HH + lane];
  nxbf[w * HH + lane] = f2bf(acc);
}

// ================= fused persistent finals =================
// 256 blocks x 1024 thr (16 waves), 1 block/CU. Stores: NORMAL (not NT) —
// L2 write-combining assembles full lines and reorders writebacks for DRAM
// page locality (the NT hint bypassed this; suspected cause of 1.75 TB/s).
#define LOADP(A, t) do { const ushort* tp_ = w1p + (size_t)(t) * 4096;           \
  _Pragma("unroll") for (int kt = 0; kt < 2; ++kt)                               \
  _Pragma("unroll") for (int nt = 0; nt < 4; ++nt)                               \
    A[kt][nt] = *(const bf16x8*)(tp_ + (kt * 4 + nt) * 512 + l * 8);             \
} while (0)

#define MFMA8(A, acc) do {                                                       \
  _Pragma("unroll") for (int kt = 0; kt < 2; ++kt)                               \
  _Pragma("unroll") for (int nt = 0; nt < 4; ++nt)                               \
    acc[nt] = __builtin_amdgcn_mfma_f32_16x16x32_bf16(A[kt][nt], bm[kt], acc[nt], 0, 0, 0); \
} while (0)

#define PROCA(A, t) do { int bn0_ = (t) * 64;                                    \
  f32x4 acc[4];                                                                  \
  _Pragma("unroll") for (int nt = 0; nt < 4; ++nt) acc[nt] = z4;                 \
  MFMA8(A, acc);                                                                 \
  _Pragma("unroll") for (int nt = 0; nt < 4; ++nt) {                             \
    int n0 = bn0_ + nt * 16 + lk * 4;                                            \
    f32x4 e4 = *(const f32x4*)(eb + n0);                                         \
    _Pragma("unroll") for (int r = 0; r < 4; ++r)                                \
      se += fexp2(acc[nt][r]) * e4[r];                                           \
  }                                                                              \
} while (0)

#define PROCB(A, t) do { int bn0_ = (t) * 64;                                    \
  f32x4 acc[4];                                                                  \
  _Pragma("unroll") for (int nt = 0; nt < 4; ++nt) acc[nt] = z4;                 \
  MFMA8(A, acc);                                                                 \
  _Pragma("unroll") for (int nt = 0; nt < 4; ++nt) {                             \
    int n0 = bn0_ + nt * 16 + lk * 4;                                            \
    f32x4 e4 = *(const f32x4*)(eb + n0);                                         \
    f32x4 vx;                                                                    \
    _Pragma("unroll") for (int r = 0; r < 4; ++r)                                \
      vx[r] = fexp2(acc[nt][r]) * e4[r] * sv;                                    \
    if (n0 < NN)                                                                 \
      *(f32x4*)(out + (size_t)(r0 + lr) * NN + n0) = vx;                         \
  }                                                                              \
} while (0)

__global__ __launch_bounds__(1024, 4) void k_fin(
    const ushort* __restrict__ nxbf, const ushort* __restrict__ w1p,
    const float* __restrict__ eb, float* __restrict__ Spart,
    int* __restrict__ bar, float* __restrict__ out)
{
  int tid = threadIdx.x;
  int l = tid & 63, w = tid >> 6;
  int lr = l & 15, lk = l >> 4;
  int b = blockIdx.x;
  int st = b & 31;
  int r0 = ((b >> 5) * 16 + w) * 16;
  int tile0 = st * TPS2;
  const f32x4 z4 = {0.f, 0.f, 0.f, 0.f};

  bf16x8 bm[2];
#pragma unroll
  for (int kt = 0; kt < 2; ++kt)
    bm[kt] = *(const bf16x8*)(nxbf + (size_t)(r0 + lr) * HH + kt * 32 + lk * 8);

  // ---- phase A: row-sums of exp over this stripe (2-deep ping-pong) ----
  float se = 0.f;
  {
    bf16x8 A0[2][4], A1[2][4];
    LOADP(A0, tile0);
#pragma unroll
    for (int i = 0; i < TPS2 / 2; ++i) {
      LOADP(A1, tile0 + 2 * i + 1);
      PROCA(A0, tile0 + 2 * i);
      if (2 * i + 2 < TPS2) LOADP(A0, tile0 + 2 * i + 2);
      PROCA(A1, tile0 + 2 * i + 1);
    }
  }
  se += __shfl_xor(se, 16);
  se += __shfl_xor(se, 32);
  if (lk == 0)
    __hip_atomic_store(&Spart[(r0 + lr) * NST2 + st], se,
                       __ATOMIC_RELAXED, __HIP_MEMORY_SCOPE_AGENT);

  // ---- device-wide barrier (256 blocks, 1/CU) ----
  __threadfence();
  __syncthreads();
  if (tid == 0) {
    __hip_atomic_fetch_add(bar, 1, __ATOMIC_ACQ_REL, __HIP_MEMORY_SCOPE_AGENT);
    while (__hip_atomic_load(bar, __ATOMIC_ACQUIRE, __HIP_MEMORY_SCOPE_AGENT) < 256)
      __builtin_amdgcn_s_sleep(2);
  }
  __syncthreads();

  // ---- Sinv for this lane's row ----
  float s = 0.f;
  {
    int myrow = r0 + lr;
    for (int j = 0; j < NST2; ++j)
      s += __hip_atomic_load(&Spart[myrow * NST2 + j],
                             __ATOMIC_RELAXED, __HIP_MEMORY_SCOPE_AGENT);
  }
  float sv = 1.0f / s;

  // ---- phase B: recompute, normalize, NORMAL stores (2-deep ping-pong) ----
  {
    bf16x8 A0[2][4], A1[2][4];
    LOADP(A0, tile0);
#pragma unroll
    for (int i = 0; i < TPS2 / 2; ++i) {
      LOADP(A1, tile0 + 2 * i + 1);
      PROCB(A0, tile0 + 2 * i);
      if (2 * i + 2 < TPS2) LOADP(A0, tile0 + 2 * i + 2);
      PROCB(A1, tile0 + 2 * i + 1);
    }
  }
}

extern "C" void kernel_launch(void* const* d_in, const int* in_sizes, int n_in,
                              void* d_out, int out_size, void* d_ws, size_t ws_size,
                              hipStream_t stream)
{
  const int* x   = (const int*)d_in[0];
  const int* src = (const int*)d_in[1];       // edge_index[0]
  const int* dst = src + NE;                  // edge_index[1]
  const int* y   = (const int*)d_in[2];
  const float* emb = (const float*)d_in[3];
  const float* Wq = (const float*)d_in[4];  const float* bq = (const float*)d_in[5];
  const float* Wk = (const float*)d_in[6];  const float* bk = (const float*)d_in[7];
  const float* Wv = (const float*)d_in[8];  const float* bv = (const float*)d_in[9];
  const float* Ws = (const float*)d_in[10]; const float* bs = (const float*)d_in[11];
  const float* W1 = (const float*)d_in[12]; const float* b1 = (const float*)d_in[13];
  float* out = (float*)d_out;

  // Persistent scratch (live across the final kernel) in d_ws.
  char* wsb = (char*)d_ws;
  ushort* nxbf  = (ushort*)wsb;                         // 2048*64*2   = 262144
  ushort* w1p   = (ushort*)(wsb + 262144);              // 53248*64*2  = 6815744 -> 7077888
  float*  Spart = (float*)(wsb + 7077888);              // 2048*32*4   = 262144  -> 7340032
  int*    bar   = (int*)(wsb + 7340032);                // 128         -> 7340160
  float*  eb    = (float*)(wsb + 7340160);              // 53248*4     = 212992  -> 7553152
  const size_t PERS  = 7553152;
  const size_t BIGSZ = 46400000;
  // Big transients are dead before k_fin writes d_out, so they may live there.
  char* big = (ws_size >= PERS + BIGSZ) ? (wsb + PERS) : (char*)d_out;
  ushort* qb     = (ushort*)(big + 0);         // 50000*64*2 = 6400000
  ushort* kb     = (ushort*)(big + 6400000);
  ushort* vb     = (ushort*)(big + 12800000);
  float*  hs     = (float*)(big + 19200000);   // 50000*64*4 = 12800000
  int2*   slot_d = (int2*)(big + 32000000);    // {src, logit-bits} per dst-CSR slot
  int* dstlist_s = (int*)(big + 38400000);     // ~33k entries (y-src edges only)
  int* rank_d    = (int*)(big + 38700000);     // NE*4 = 3200000
  int* rank_s    = (int*)(big + 41900000);     // NE*4 = 3200000
  int* cnt_d     = (int*)(big + 45100000);
  int* cnt_s     = (int*)(big + 45300000);
  int* indptr_d  = (int*)(big + 45500000);
  int* indptr_s  = (int*)(big + 45700064);
  char* flag     = (char*)(big + 45900128);
  char* ymark    = (char*)(big + 45950176);
  ushort* WT     = (ushort*)(big + 46000224);  // 4*64*64*2 = 32768

  k_prep<<<dim3(224), dim3(256), 0, stream>>>(W1, b1, Wq, Wk, Wv, Ws, w1p, eb, WT,
                                              cnt_d, cnt_s, flag, ymark, bar);
  k_mark<<<dim3(8), dim3(256), 0, stream>>>(y, ymark);
  k_hq<<<dim3(HBLK + QBLK), dim3(256), 0, stream>>>(src, dst, ymark,
                                                    cnt_s, cnt_d, flag, rank_d, rank_s,
                                                    x, emb, WT, bq, bk, bv, bs,
                                                    qb, kb, vb, hs);
  k_scan<<<dim3(2), dim3(1024), 0, stream>>>(cnt_d, indptr_d, cnt_s, indptr_s);
  k_efill<<<dim3(12500), dim3(256), 0, stream>>>(src, dst, qb, kb, flag,
                                                 indptr_s, indptr_d, rank_d, rank_s,
                                                 dstlist_s, slot_d);
  k_agg<<<dim3(12500), dim3(256), 0, stream>>>(indptr_d, slot_d, vb, flag, hs);
  k_newx<<<dim3(512), dim3(256), 0, stream>>>(y, indptr_s, dstlist_s, hs, nxbf);
  k_fin<<<dim3(256), dim3(1024), 0, stream>>>(nxbf, w1p, eb, Spart, bar, out);
}

// Round 16
// 439.847 us; speedup vs baseline: 1.5715x; 1.5715x over previous
//
#include <hip/hip_runtime.h>
#include <math.h>

#define NN 50000   // nodes
#define NE 800000  // edges
#define HH 64      // hidden
#define NB 2048    // batch |y|
#define NPAD 53248 // padded cols = 832 tiles of 64
#define NST3 52    // stripes in finals (52 x 16 tiles = 832)
#define TPS3 16
#define LOG2E 1.4426950408889634f
#define HBLK 3125  // hist blocks in fused k_hq
#define QBLK 782   // qkvs blocks in fused k_hq

typedef __attribute__((ext_vector_type(8))) short bf16x8;
typedef __attribute__((ext_vector_type(4))) float f32x4;

__device__ inline ushort f2bf(float f) {  // round-to-nearest-even f32->bf16
  uint u = __float_as_uint(f);
  uint r = (u + 0x7fffu + ((u >> 16) & 1u)) >> 16;
  return (ushort)r;
}
__device__ inline float bf2f(uint u) { return __uint_as_float(u << 16); }

__device__ inline float fexp2(float x) {
#if __has_builtin(__builtin_amdgcn_exp2f)
  return __builtin_amdgcn_exp2f(x);
#else
  return exp2f(x);
#endif
}

// ---------------- prep: zero counters/flags + fragment-permuted W1 + eb + WT ----------------
__global__ __launch_bounds__(256) void k_prep(
    const float* __restrict__ W1, const float* __restrict__ b1,
    const float* __restrict__ Wq, const float* __restrict__ Wk,
    const float* __restrict__ Wv, const float* __restrict__ Ws,
    ushort* __restrict__ w1p, float* __restrict__ eb, ushort* __restrict__ WT,
    int* cnt_d, int* cnt_s, char* flag, char* ymark)
{
  int i = blockIdx.x * 256 + threadIdx.x;  // grid 224*256 = 57344 >= NPAD
  if (i < NN) { cnt_d[i] = 0; cnt_s[i] = 0; flag[i] = 0; ymark[i] = 0; }
  if (i < 4 * HH * HH) {
    int m = i >> 12, rem = i & 4095;
    int c = rem >> 6, kk = rem & 63;
    const float* W = (m == 0) ? Wq : (m == 1) ? Wk : (m == 2) ? Wv : Ws;
    WT[i] = f2bf(W[kk * HH + c]);
  }
  if (i < NPAD) {
    eb[i] = (i < NN) ? __expf(b1[i]) : 0.f;
    uint4 o[8];
    ushort* op = (ushort*)o;
    if (i < NN) {
#pragma unroll
      for (int k = 0; k < HH; ++k) op[k] = f2bf(W1[(size_t)k * NN + i] * LOG2E);
    } else {
#pragma unroll
      for (int k = 0; k < HH; ++k) op[k] = 0;
    }
    int t = i >> 6, nt = (i >> 4) & 3, lr = i & 15;
    ushort* tp = w1p + (size_t)t * 4096;
#pragma unroll
    for (int kt = 0; kt < 2; ++kt)
#pragma unroll
      for (int lk = 0; lk < 4; ++lk)
        *(uint4*)(tp + (kt * 4 + nt) * 512 + (lk * 16 + lr) * 8) = o[kt * 4 + lk];
  }
}

// ---------------- mark y-membership ----------------
__global__ __launch_bounds__(256) void k_mark(const int* __restrict__ y,
                                              char* __restrict__ ymark) {
  int i = blockIdx.x * 256 + threadIdx.x;
  if (i < NB) ymark[y[i]] = 1;
}

// ---------------- FUSED: hist (blocks 0..HBLK-1) + qkvs (blocks HBLK..) ----------------
__global__ __launch_bounds__(256) void k_hq(
    const int* __restrict__ src, const int* __restrict__ dst,
    const char* __restrict__ ymark,
    int* cnt_s, int* cnt_d, char* __restrict__ flag,
    int* __restrict__ rank_d, int* __restrict__ rank_s,
    const int* __restrict__ x, const float* __restrict__ emb,
    const ushort* __restrict__ WT,
    const float* __restrict__ bq, const float* __restrict__ bk,
    const float* __restrict__ bv, const float* __restrict__ bs,
    ushort* __restrict__ qb, ushort* __restrict__ kb, ushort* __restrict__ vb,
    float* __restrict__ hs)
{
  if (blockIdx.x < HBLK) {
    int e = blockIdx.x * 256 + threadIdx.x;
    if (e < NE) {
      int s = src[e], d = dst[e];
      rank_d[e] = atomicAdd(&cnt_d[d], 1);
      if (ymark[s]) {
        rank_s[e] = atomicAdd(&cnt_s[s], 1);
        flag[d] = 1;
      } else {
        rank_s[e] = -1;
      }
    }
    return;
  }
  int l = threadIdx.x & 63, w = threadIdx.x >> 6;
  int lr = l & 15, lk = l >> 4;
  int r0 = (blockIdx.x - HBLK) * 64;
  const ushort* wt = WT + w * HH * HH;
  const float* B = (w == 0) ? bq : (w == 1) ? bk : (w == 2) ? bv : bs;

  bf16x8 b[2][4];
#pragma unroll
  for (int kt = 0; kt < 2; ++kt)
#pragma unroll
    for (int nt = 0; nt < 4; ++nt)
      b[kt][nt] = *(const bf16x8*)(wt + (nt * 16 + lr) * HH + kt * 32 + lk * 8);

  bf16x8 a[2][4];
#pragma unroll
  for (int mt = 0; mt < 4; ++mt) {
    int row = r0 + mt * 16 + lr;
    int g = (row < NN) ? x[row] : 0;
    const float* hp = emb + (size_t)g * HH;
#pragma unroll
    for (int kt = 0; kt < 2; ++kt) {
      float4 f0 = *(const float4*)(hp + kt * 32 + lk * 8);
      float4 f1 = *(const float4*)(hp + kt * 32 + lk * 8 + 4);
      bf16x8 af;
      af[0] = f2bf(f0.x); af[1] = f2bf(f0.y); af[2] = f2bf(f0.z); af[3] = f2bf(f0.w);
      af[4] = f2bf(f1.x); af[5] = f2bf(f1.y); af[6] = f2bf(f1.z); af[7] = f2bf(f1.w);
      a[kt][mt] = af;
    }
  }

  f32x4 acc[4][4];
  const f32x4 z4 = {0.f, 0.f, 0.f, 0.f};
#pragma unroll
  for (int mt = 0; mt < 4; ++mt)
#pragma unroll
    for (int nt = 0; nt < 4; ++nt) acc[mt][nt] = z4;
#pragma unroll
  for (int kt = 0; kt < 2; ++kt)
#pragma unroll
    for (int mt = 0; mt < 4; ++mt)
#pragma unroll
      for (int nt = 0; nt < 4; ++nt)
        acc[mt][nt] = __builtin_amdgcn_mfma_f32_16x16x32_bf16(a[kt][mt], b[kt][nt], acc[mt][nt], 0, 0, 0);

  if (w < 3) {
    ushort* Db = (w == 0) ? qb : (w == 1) ? kb : vb;
#pragma unroll
    for (int mt = 0; mt < 4; ++mt)
#pragma unroll
      for (int r = 0; r < 4; ++r) {
        int row = r0 + mt * 16 + lk * 4 + r;
        if (row < NN) {
#pragma unroll
          for (int nt = 0; nt < 4; ++nt) {
            int c = nt * 16 + lr;
            Db[(size_t)row * HH + c] = f2bf(acc[mt][nt][r] + B[c]);
          }
        }
      }
  } else {
#pragma unroll
    for (int mt = 0; mt < 4; ++mt)
#pragma unroll
      for (int r = 0; r < 4; ++r) {
        int row = r0 + mt * 16 + lk * 4 + r;
        if (row < NN) {
#pragma unroll
          for (int nt = 0; nt < 4; ++nt) {
            int c = nt * 16 + lr;
            hs[(size_t)row * HH + c] = acc[mt][nt][r] + B[c];
          }
        }
      }
  }
}

// ---------------- CSR build: exclusive scan (1 block per array) ----------------
__global__ __launch_bounds__(1024) void k_scan(
    const int* __restrict__ cnt_d, int* indptr_d,
    const int* __restrict__ cnt_s, int* indptr_s)
{
  const int* cnt = (blockIdx.x == 0) ? cnt_d : cnt_s;
  int* indptr    = (blockIdx.x == 0) ? indptr_d : indptr_s;
  __shared__ int sums[1024];
  const int CH = (NN + 1023) / 1024;  // 49
  int t = threadIdx.x;
  int begin = t * CH;
  int end = begin + CH; if (end > NN) end = NN;
  int s = 0;
  for (int i = begin; i < end; ++i) s += cnt[i];
  sums[t] = s;
  __syncthreads();
  for (int off = 1; off < 1024; off <<= 1) {
    int val = (t >= off) ? sums[t - off] : 0;
    __syncthreads();
    sums[t] += val;
    __syncthreads();
  }
  int prefix = (t == 0) ? 0 : sums[t - 1];
  for (int i = begin; i < end; ++i) {
    indptr[i] = prefix;
    prefix += cnt[i];
  }
  if (t == 0) indptr[NN] = sums[1023];
}

// ---------------- fused logits (flag-gated, bf16) + rank-addressed CSR fill ----------------
__global__ __launch_bounds__(256) void k_efill(
    const int* __restrict__ src, const int* __restrict__ dst,
    const ushort* __restrict__ qb, const ushort* __restrict__ kb,
    const char* __restrict__ flag,
    const int* __restrict__ indptr_s, const int* __restrict__ indptr_d,
    const int* __restrict__ rank_d, const int* __restrict__ rank_s,
    int* __restrict__ dstlist_s, int2* __restrict__ slot_d)
{
  int gid = blockIdx.x * 256 + threadIdx.x;
  int e = gid >> 2;
  int lane = gid & 3;
  if (e >= NE) return;
  int s = src[e], d = dst[e];
  bool fd = flag[d];
  float p = 0.f;
  if (fd) {
    const uint4* qp = (const uint4*)(qb + (size_t)d * HH + lane * 16);
    const uint4* kp = (const uint4*)(kb + (size_t)s * HH + lane * 16);
    uint4 qa0 = qp[0], ka0 = kp[0];
    uint4 qa1 = qp[1], ka1 = kp[1];
    p += bf2f(qa0.x & 0xffffu) * bf2f(ka0.x & 0xffffu) + bf2f(qa0.x >> 16) * bf2f(ka0.x >> 16);
    p += bf2f(qa0.y & 0xffffu) * bf2f(ka0.y & 0xffffu) + bf2f(qa0.y >> 16) * bf2f(ka0.y >> 16);
    p += bf2f(qa0.z & 0xffffu) * bf2f(ka0.z & 0xffffu) + bf2f(qa0.z >> 16) * bf2f(ka0.z >> 16);
    p += bf2f(qa0.w & 0xffffu) * bf2f(ka0.w & 0xffffu) + bf2f(qa0.w >> 16) * bf2f(ka0.w >> 16);
    p += bf2f(qa1.x & 0xffffu) * bf2f(ka1.x & 0xffffu) + bf2f(qa1.x >> 16) * bf2f(ka1.x >> 16);
    p += bf2f(qa1.y & 0xffffu) * bf2f(ka1.y & 0xffffu) + bf2f(qa1.y >> 16) * bf2f(ka1.y >> 16);
    p += bf2f(qa1.z & 0xffffu) * bf2f(ka1.z & 0xffffu) + bf2f(qa1.z >> 16) * bf2f(ka1.z >> 16);
    p += bf2f(qa1.w & 0xffffu) * bf2f(ka1.w & 0xffffu) + bf2f(qa1.w >> 16) * bf2f(ka1.w >> 16);
    p += __shfl_xor(p, 2);
    p += __shfl_xor(p, 1);
  }
  if (lane == 0) {
    if (fd) {
      int pd = indptr_d[d] + rank_d[e];
      int2 sl; sl.x = s; sl.y = __float_as_int(p * (0.125f * LOG2E));
      slot_d[pd] = sl;
    }
    int rs = rank_s[e];
    if (rs >= 0) dstlist_s[indptr_s[s] + rs] = d;
  }
}

// ---------------- per-dst softmax + weighted v aggregation (flagged only) ----------------
__global__ __launch_bounds__(256) void k_agg(
    const int* __restrict__ indptr_d, const int2* __restrict__ slot_d,
    const ushort* __restrict__ vb, const char* __restrict__ flag,
    float* __restrict__ hs)
{
  int w = (blockIdx.x * 256 + threadIdx.x) >> 6;  // node id, one wave each
  int lane = threadIdx.x & 63;                    // hidden dim
  if (w >= NN) return;
  if (!flag[w]) return;
  int beg = indptr_d[w], end = indptr_d[w + 1];
  if (beg == end) return;
  float den0 = 0.f, den1 = 0.f, acc0 = 0.f, acc1 = 0.f;
  int j = beg;
  for (; j + 1 < end; j += 2) {
    int2 sa = slot_d[j];
    int2 sb = slot_d[j + 1];
    float pa = fexp2(__int_as_float(sa.y));
    float pb = fexp2(__int_as_float(sb.y));
    float va = bf2f((uint)vb[(size_t)sa.x * HH + lane]);
    float vc = bf2f((uint)vb[(size_t)sb.x * HH + lane]);
    den0 += pa; den1 += pb;
    acc0 = fmaf(pa, va, acc0);
    acc1 = fmaf(pb, vc, acc1);
  }
  if (j < end) {
    int2 sa = slot_d[j];
    float pa = fexp2(__int_as_float(sa.y));
    den0 += pa;
    acc0 = fmaf(pa, bf2f((uint)vb[(size_t)sa.x * HH + lane]), acc0);
  }
  hs[(size_t)w * HH + lane] += (acc0 + acc1) / (den0 + den1);
}

// ---------------- new_x[b] = sum_{e: src==y[b]} out[dst[e]]  (written as bf16) ----------------
__global__ __launch_bounds__(256) void k_newx(
    const int* __restrict__ y, const int* __restrict__ indptr_s,
    const int* __restrict__ dstlist_s, const float* __restrict__ outn,
    ushort* __restrict__ nxbf)
{
  int w = (blockIdx.x * 256 + threadIdx.x) >> 6;
  int lane = threadIdx.x & 63;
  if (w >= NB) return;
  int u = y[w];
  int beg = indptr_s[u], end = indptr_s[u + 1];
  float acc = 0.f;
  for (int j = beg; j < end; ++j) acc += outn[(size_t)dstlist_s[j] * HH + lane];
  nxbf[w * HH + lane] = f2bf(acc);
}

// ================= finals =================
#define LOADP(A, t) do { const ushort* tp_ = w1p + (size_t)(t) * 4096;           \
  _Pragma("unroll") for (int kt = 0; kt < 2; ++kt)                               \
  _Pragma("unroll") for (int nt = 0; nt < 4; ++nt)                               \
    A[kt][nt] = *(const bf16x8*)(tp_ + (kt * 4 + nt) * 512 + l * 8);             \
} while (0)

#define MFMA8(A, acc) do {                                                       \
  _Pragma("unroll") for (int kt = 0; kt < 2; ++kt)                               \
  _Pragma("unroll") for (int nt = 0; nt < 4; ++nt)                               \
    acc[nt] = __builtin_amdgcn_mfma_f32_16x16x32_bf16(A[kt][nt], bm[kt], acc[nt], 0, 0, 0); \
} while (0)

// ---- k_finZ: single GEMM -> u fp16 (LDS transpose, full-line stores) + Spart ----
// 1664 blocks = 52 stripes x 32 rowgroups; 4 waves x 16 rows; 2 supertiles of 8.
// LDS per wave [16][512] ushort, XOR-swizzled (8B unit uP = uL ^ 2*(lr&7)).
__global__ __launch_bounds__(256) void k_finZ(
    const ushort* __restrict__ nxbf, const ushort* __restrict__ w1p,
    const float* __restrict__ eb, ushort* __restrict__ zb,
    float* __restrict__ Spart)
{
  __shared__ ushort lt[4][16][512];   // 64KB
  int tid = threadIdx.x;
  int l = tid & 63, w = tid >> 6;
  int lr = l & 15, lk = l >> 4;
  int b = blockIdx.x;
  int st = b % NST3, rg = b / NST3;
  int r0 = rg * 64 + w * 16;
  int tile0 = st * TPS3;
  const f32x4 z4 = {0.f, 0.f, 0.f, 0.f};

  bf16x8 bm[2];
#pragma unroll
  for (int kt = 0; kt < 2; ++kt)
    bm[kt] = *(const bf16x8*)(nxbf + (size_t)(r0 + lr) * HH + kt * 32 + lk * 8);

  float se = 0.f;
#pragma unroll
  for (int s = 0; s < 2; ++s) {
#pragma unroll
    for (int t = 0; t < 8; ++t) {
      int tile = tile0 + s * 8 + t;
      bf16x8 A0[2][4];
      LOADP(A0, tile);
      f32x4 acc[4];
#pragma unroll
      for (int nt = 0; nt < 4; ++nt) acc[nt] = z4;
      MFMA8(A0, acc);
#pragma unroll
      for (int nt = 0; nt < 4; ++nt) {
        int n0 = tile * 64 + nt * 16 + lk * 4;
        f32x4 e4 = *(const f32x4*)(eb + n0);
        union { _Float16 h[4]; uint2 u; } pk;
#pragma unroll
        for (int r = 0; r < 4; ++r) {
          float ur = fexp2(acc[nt][r]) * e4[r];
          se += ur;
          pk.h[r] = (_Float16)ur;
        }
        int uL = t * 16 + nt * 4 + lk;
        int uP = uL ^ (2 * (lr & 7));
        *(uint2*)&lt[w][lr][uP * 4] = pk.u;
      }
    }
    // flush supertile: 16 full-line 1024B stores (one row each)
    int colbase = (tile0 + s * 8) * 64;
#pragma unroll
    for (int r = 0; r < 16; ++r) {
      uint4 v = *(const uint4*)&lt[w][r][(l ^ (r & 7)) * 8];
      *(uint4*)(zb + (size_t)(r0 + r) * NPAD + colbase + l * 8) = v;
    }
  }
  se += __shfl_xor(se, 16);
  se += __shfl_xor(se, 32);
  if (lk == 0) Spart[(r0 + lr) * NST3 + st] = se;
}

// ---- Sinv[row] = 1 / sum_st Spart ----
__global__ __launch_bounds__(256) void k_sinv(const float* __restrict__ Spart,
                                              float* __restrict__ Sinv) {
  int r = blockIdx.x * 256 + threadIdx.x;
  if (r < NB) {
    float s = 0.f;
#pragma unroll
    for (int j = 0; j < NST3; ++j) s += Spart[r * NST3 + j];
    Sinv[r] = 1.0f / s;
  }
}

// ---- k_finN: streaming normalize, fill-shaped both sides ----
__global__ __launch_bounds__(256) void k_finN(
    const ushort* __restrict__ zb, const float* __restrict__ Sinv,
    float* __restrict__ out)
{
  int r = blockIdx.x;
  float sv = Sinv[r];
  const ushort* zr = zb + (size_t)r * NPAD;
  float* orow = out + (size_t)r * NN;
  for (int c0 = threadIdx.x * 8; c0 < NN; c0 += 2048) {   // NN % 8 == 0
    uint4 zv = *(const uint4*)(zr + c0);
    const _Float16* hp = (const _Float16*)&zv;
    f32x4 v0, v1;
#pragma unroll
    for (int j = 0; j < 4; ++j) {
      v0[j] = (float)hp[j] * sv;
      v1[j] = (float)hp[4 + j] * sv;
    }
    *(f32x4*)(orow + c0) = v0;
    *(f32x4*)(orow + c0 + 4) = v1;
  }
}

// ---- fallback (ws too small): two-pass NT-scatter finals ----
#define PROCA(A, t) do { int bn0_ = (t) * 64;                                    \
  f32x4 acc[4];                                                                  \
  _Pragma("unroll") for (int nt = 0; nt < 4; ++nt) acc[nt] = z4;                 \
  MFMA8(A, acc);                                                                 \
  _Pragma("unroll") for (int nt = 0; nt < 4; ++nt) {                             \
    int n0 = bn0_ + nt * 16 + lk * 4;                                            \
    f32x4 e4 = *(const f32x4*)(eb + n0);                                         \
    _Pragma("unroll") for (int r = 0; r < 4; ++r)                                \
      se += fexp2(acc[nt][r]) * e4[r];                                           \
  }                                                                              \
} while (0)

#define PROCB(A, t) do { int bn0_ = (t) * 64;                                    \
  f32x4 acc[4];                                                                  \
  _Pragma("unroll") for (int nt = 0; nt < 4; ++nt) acc[nt] = z4;                 \
  MFMA8(A, acc);                                                                 \
  _Pragma("unroll") for (int nt = 0; nt < 4; ++nt) {                             \
    int n0 = bn0_ + nt * 16 + lk * 4;                                            \
    f32x4 e4 = *(const f32x4*)(eb + n0);                                         \
    f32x4 vx;                                                                    \
    _Pragma("unroll") for (int r = 0; r < 4; ++r)                                \
      vx[r] = fexp2(acc[nt][r]) * e4[r] * sv;                                    \
    if (n0 < NN)                                                                 \
      __builtin_nontemporal_store(vx, (f32x4*)(out + (size_t)(r0 + lr) * NN + n0)); \
  }                                                                              \
} while (0)

__global__ __launch_bounds__(256, 4) void k_finA(
    const ushort* __restrict__ nxbf, const ushort* __restrict__ w1p,
    const float* __restrict__ eb, float* __restrict__ Spart)
{
  int tid = threadIdx.x;
  int l = tid & 63, w = tid >> 6;
  int lr = l & 15, lk = l >> 4;
  int b = blockIdx.x;
  int st = b % NST3, rg = b / NST3;
  int r0 = rg * 64 + w * 16;
  int tile0 = st * TPS3;
  const f32x4 z4 = {0.f, 0.f, 0.f, 0.f};
  bf16x8 bm[2];
#pragma unroll
  for (int kt = 0; kt < 2; ++kt)
    bm[kt] = *(const bf16x8*)(nxbf + (size_t)(r0 + lr) * HH + kt * 32 + lk * 8);
  float se = 0.f;
  {
    bf16x8 A0[2][4];
#pragma unroll
    for (int t = 0; t < TPS3; ++t) { LOADP(A0, tile0 + t); PROCA(A0, tile0 + t); }
  }
  se += __shfl_xor(se, 16);
  se += __shfl_xor(se, 32);
  if (lk == 0) Spart[(r0 + lr) * NST3 + st] = se;
}

__global__ __launch_bounds__(256, 4) void k_finB(
    const ushort* __restrict__ nxbf, const ushort* __restrict__ w1p,
    const float* __restrict__ eb, const float* __restrict__ Sinv,
    float* __restrict__ out)
{
  int tid = threadIdx.x;
  int l = tid & 63, w = tid >> 6;
  int lr = l & 15, lk = l >> 4;
  int b = blockIdx.x;
  int st = b % NST3, rg = b / NST3;
  int r0 = rg * 64 + w * 16;
  int tile0 = st * TPS3;
  const f32x4 z4 = {0.f, 0.f, 0.f, 0.f};
  bf16x8 bm[2];
#pragma unroll
  for (int kt = 0; kt < 2; ++kt)
    bm[kt] = *(const bf16x8*)(nxbf + (size_t)(r0 + lr) * HH + kt * 32 + lk * 8);
  float sv = Sinv[r0 + lr];
  {
    bf16x8 A0[2][4];
#pragma unroll
    for (int t = 0; t < TPS3; ++t) { LOADP(A0, tile0 + t); PROCB(A0, tile0 + t); }
  }
}

extern "C" void kernel_launch(void* const* d_in, const int* in_sizes, int n_in,
                              void* d_out, int out_size, void* d_ws, size_t ws_size,
                              hipStream_t stream)
{
  const int* x   = (const int*)d_in[0];
  const int* src = (const int*)d_in[1];       // edge_index[0]
  const int* dst = src + NE;                  // edge_index[1]
  const int* y   = (const int*)d_in[2];
  const float* emb = (const float*)d_in[3];
  const float* Wq = (const float*)d_in[4];  const float* bq = (const float*)d_in[5];
  const float* Wk = (const float*)d_in[6];  const float* bk = (const float*)d_in[7];
  const float* Wv = (const float*)d_in[8];  const float* bv = (const float*)d_in[9];
  const float* Ws = (const float*)d_in[10]; const float* bs = (const float*)d_in[11];
  const float* W1 = (const float*)d_in[12]; const float* b1 = (const float*)d_in[13];
  float* out = (float*)d_out;

  char* wsb = (char*)d_ws;
  ushort* nxbf  = (ushort*)wsb;                         // 262144
  ushort* w1p   = (ushort*)(wsb + 262144);              // 6815744 -> 7077888
  float*  Spart = (float*)(wsb + 7077888);              // 2048*52*4 = 425984 -> 7503872
  float*  Sinv  = (float*)(wsb + 7503872);              // 8192 -> 7512064
  float*  eb    = (float*)(wsb + 7512064);              // 212992 -> 7725056
  const size_t PERS   = 7725056;
  const size_t ZSZ    = (size_t)NB * NPAD * 2;          // 218103808
  const size_t PERS_Z = PERS + ZSZ;                     // 225828864
  const size_t BIGSZ  = 46400000;
  bool zpath = ws_size >= PERS_Z + BIGSZ;
  ushort* zb = (ushort*)(wsb + PERS);
  char* big = zpath ? (wsb + PERS_Z)
                    : ((ws_size >= PERS + BIGSZ) ? (wsb + PERS) : (char*)d_out);
  ushort* qb     = (ushort*)(big + 0);
  ushort* kb     = (ushort*)(big + 6400000);
  ushort* vb     = (ushort*)(big + 12800000);
  float*  hs     = (float*)(big + 19200000);
  int2*   slot_d = (int2*)(big + 32000000);
  int* dstlist_s = (int*)(big + 38400000);
  int* rank_d    = (int*)(big + 38700000);
  int* rank_s    = (int*)(big + 41900000);
  int* cnt_d     = (int*)(big + 45100000);
  int* cnt_s     = (int*)(big + 45300000);
  int* indptr_d  = (int*)(big + 45500000);
  int* indptr_s  = (int*)(big + 45700064);
  char* flag     = (char*)(big + 45900128);
  char* ymark    = (char*)(big + 45950176);
  ushort* WT     = (ushort*)(big + 46000224);

  k_prep<<<dim3(224), dim3(256), 0, stream>>>(W1, b1, Wq, Wk, Wv, Ws, w1p, eb, WT,
                                              cnt_d, cnt_s, flag, ymark);
  k_mark<<<dim3(8), dim3(256), 0, stream>>>(y, ymark);
  k_hq<<<dim3(HBLK + QBLK), dim3(256), 0, stream>>>(src, dst, ymark,
                                                    cnt_s, cnt_d, flag, rank_d, rank_s,
                                                    x, emb, WT, bq, bk, bv, bs,
                                                    qb, kb, vb, hs);
  k_scan<<<dim3(2), dim3(1024), 0, stream>>>(cnt_d, indptr_d, cnt_s, indptr_s);
  k_efill<<<dim3(12500), dim3(256), 0, stream>>>(src, dst, qb, kb, flag,
                                                 indptr_s, indptr_d, rank_d, rank_s,
                                                 dstlist_s, slot_d);
  k_agg<<<dim3(12500), dim3(256), 0, stream>>>(indptr_d, slot_d, vb, flag, hs);
  k_newx<<<dim3(512), dim3(256), 0, stream>>>(y, indptr_s, dstlist_s, hs, nxbf);
  if (zpath) {
    k_finZ<<<dim3(NST3 * 32), dim3(256), 0, stream>>>(nxbf, w1p, eb, zb, Spart);
    k_sinv<<<dim3(8), dim3(256), 0, stream>>>(Spart, Sinv);
    k_finN<<<dim3(NB), dim3(256), 0, stream>>>(zb, Sinv, out);
  } else {
    k_finA<<<dim3(NST3 * 32), dim3(256), 0, stream>>>(nxbf, w1p, eb, Spart);
    k_sinv<<<dim3(8), dim3(256), 0, stream>>>(Spart, Sinv);
    k_finB<<<dim3(NST3 * 32), dim3(256), 0, stream>>>(nxbf, w1p, eb, Sinv, out);
  }
}